// Round 3
// baseline (84.990 us; speedup 1.0000x reference)
//
#include <hip/hip_runtime.h>

#define IMG 256
#define TX 64
#define TY 16
#define LH 22          // staged rows: gy0-3 .. gy0+18
#define LSTRIDE 72     // staged cols: gx0-4 .. gx0+67 (16B-aligned both ends)
#define NCHUNK (LH * (LSTRIDE / 4))   // 22*18 = 396 float4 chunks

__device__ __forceinline__ int reflect_idx(int i) {
    // jnp.pad mode="reflect": -1 -> 1, 256 -> 254
    i = i < 0 ? -i : i;
    i = i > (IMG - 1) ? 2 * (IMG - 1) - i : i;
    return i;
}

// Per-pixel horizontal window for pixel p lives at w[p+1..p+7] of the
// 12-float segment starting at local col col0 (w0/w11 are alignment slack).
// Row pair dr=+/-d shares multiplier e_d; rsum is linear in x, so rows are
// summed first (w = rowA + rowB), then one horizontal rsum + one fma each.
#define ACCUM_PAIR(RA, RB, E0, E1, E2, E3)                                    \
  {                                                                           \
    const float* pa = &tile[(RA) * LSTRIDE + col0];                           \
    const float* pb = &tile[(RB) * LSTRIDE + col0];                           \
    const float4 a0 = *(const float4*)pa;                                     \
    const float4 a1 = *(const float4*)(pa + 4);                               \
    const float4 a2 = *(const float4*)(pa + 8);                               \
    const float4 b0 = *(const float4*)pb;                                     \
    const float4 b1 = *(const float4*)(pb + 4);                               \
    const float4 b2 = *(const float4*)(pb + 8);                               \
    const float w1 = a0.y + b0.y, w2 = a0.z + b0.z, w3 = a0.w + b0.w;         \
    const float w4 = a1.x + b1.x, w5 = a1.y + b1.y, w6 = a1.z + b1.z;         \
    const float w7 = a1.w + b1.w, w8 = a2.x + b2.x, w9 = a2.y + b2.y;         \
    const float w10 = a2.z + b2.z;                                            \
    acc_0 += (E0) * (w4 + e1_0 * (w3 + w5) + e2_0 * (w2 + w6) + e3_0 * (w1 + w7)); \
    acc_1 += (E1) * (w5 + e1_1 * (w4 + w6) + e2_1 * (w3 + w7) + e3_1 * (w2 + w8)); \
    acc_2 += (E2) * (w6 + e1_2 * (w5 + w7) + e2_2 * (w4 + w8) + e3_2 * (w3 + w9)); \
    acc_3 += (E3) * (w7 + e1_3 * (w6 + w8) + e2_3 * (w5 + w9) + e3_3 * (w4 + w10)); \
  }

#define ACCUM_CENTER(RC)                                                      \
  {                                                                           \
    const float* pc = &tile[(RC) * LSTRIDE + col0];                           \
    const float4 c0 = *(const float4*)pc;                                     \
    const float4 c1 = *(const float4*)(pc + 4);                               \
    const float4 c2 = *(const float4*)(pc + 8);                               \
    const float w1 = c0.y, w2 = c0.z, w3 = c0.w;                              \
    const float w4 = c1.x, w5 = c1.y, w6 = c1.z, w7 = c1.w;                   \
    const float w8 = c2.x, w9 = c2.y, w10 = c2.z;                             \
    acc_0 += w4 + e1_0 * (w3 + w5) + e2_0 * (w2 + w6) + e3_0 * (w1 + w7);     \
    acc_1 += w5 + e1_1 * (w4 + w6) + e2_1 * (w3 + w7) + e3_1 * (w2 + w8);     \
    acc_2 += w6 + e1_2 * (w5 + w7) + e2_2 * (w4 + w8) + e3_2 * (w3 + w9);     \
    acc_3 += w7 + e1_3 * (w6 + w8) + e2_3 * (w5 + w9) + e3_3 * (w4 + w10);    \
  }

#define COEF(P, SV)                                                           \
  float e1_##P, e2_##P, e3_##P, inv_##P;                                      \
  {                                                                           \
    const float s2 = (SV) * (SV);                                             \
    const float a = __expf(-0.5f * s2);  /* e1 = exp(-1/2 s^2) */             \
    const float t = a * a;                                                    \
    const float b = t * t;               /* e1^4 = e2 */                      \
    const float c = b * b * a;           /* e1^9 = e3 */                      \
    e1_##P = a; e2_##P = b; e3_##P = c;                                       \
    const float S = 1.0f + 2.0f * (a + b + c);                                \
    inv_##P = __builtin_amdgcn_rcpf(S * S);                                   \
  }

__global__ __launch_bounds__(256)
void agf_kernel(const float* __restrict__ x, const float* __restrict__ sigma,
                float* __restrict__ out) {
    __shared__ float tile[LH * LSTRIDE];

    const int plane = blockIdx.z;                 // b*C + c, 0..47
    const int gx0 = blockIdx.x * TX;
    const int gy0 = blockIdx.y * TY;
    const int tid = threadIdx.x;

    const float* xp = x + (size_t)plane * (IMG * IMG);

    const int tx = tid & 15;       // 0..15
    const int ty = tid >> 4;       // 0..15
    const int col0 = tx * 4;       // pixel p: global col gx0+col0+p, local col0+p+4
    const size_t gbase = (size_t)plane * (IMG * IMG) + (size_t)(gy0 + ty) * IMG + gx0 + col0;

    // issue the sigma load first so it overlaps staging
    const float4 sg = *reinterpret_cast<const float4*>(sigma + gbase);

    // ---- stage x tile into LDS: float4 chunks, local col lc <-> global gx0-4+lc ----
    #pragma unroll
    for (int it = 0; it < 2; ++it) {
        const int idx = tid + it * 256;
        if (idx < NCHUNK) {
            const int lr = idx / 18;              // chunk row
            const int lc4 = idx - lr * 18;
            const int lcol = lc4 * 4;
            const int grow = reflect_idx(gy0 - 3 + lr);
            const int gcol = gx0 - 4 + lcol;
            const float* src = xp + (size_t)grow * IMG;
            if (gcol >= 0 && gcol <= IMG - 4) {   // aligned vector fast path
                *reinterpret_cast<float4*>(&tile[lr * LSTRIDE + lcol]) =
                    *reinterpret_cast<const float4*>(src + gcol);
            } else {                              // edge chunks: per-element reflect
                #pragma unroll
                for (int j = 0; j < 4; ++j)
                    tile[lr * LSTRIDE + lcol + j] = src[reflect_idx(gcol + j)];
            }
        }
    }

    // per-pixel coefficients — independent of LDS, computed before the barrier
    COEF(0, sg.x)
    COEF(1, sg.y)
    COEF(2, sg.z)
    COEF(3, sg.w)
    float acc_0 = 0.0f, acc_1 = 0.0f, acc_2 = 0.0f, acc_3 = 0.0f;

    __syncthreads();

    ACCUM_PAIR(ty + 0, ty + 6, e3_0, e3_1, e3_2, e3_3)   // dr = +/-3
    ACCUM_PAIR(ty + 1, ty + 5, e2_0, e2_1, e2_2, e2_3)   // dr = +/-2
    ACCUM_PAIR(ty + 2, ty + 4, e1_0, e1_1, e1_2, e1_3)   // dr = +/-1
    ACCUM_CENTER(ty + 3)                                 // dr = 0

    float4 o;
    o.x = acc_0 * inv_0;
    o.y = acc_1 * inv_1;
    o.z = acc_2 * inv_2;
    o.w = acc_3 * inv_3;
    *reinterpret_cast<float4*>(out + gbase) = o;
}

extern "C" void kernel_launch(void* const* d_in, const int* in_sizes, int n_in,
                              void* d_out, int out_size, void* d_ws, size_t ws_size,
                              hipStream_t stream) {
    const float* x = (const float*)d_in[0];
    const float* sigma = (const float*)d_in[1];
    float* out = (float*)d_out;

    const int planes = in_sizes[0] / (IMG * IMG);   // 16*3 = 48
    dim3 grid(IMG / TX, IMG / TY, planes);          // (4, 16, 48)
    agf_kernel<<<grid, 256, 0, stream>>>(x, sigma, out);
}